// Round 1
// baseline (203.443 us; speedup 1.0000x reference)
//
#include <hip/hip_runtime.h>

// One wave (64 lanes) handles one batch element end-to-end.
// Lane mapping: t = lane&15 (softmax row / MFMA M-dim), q = lane>>4 (K quad).
typedef __attribute__((ext_vector_type(8))) short short8;   // 8 bf16 (4 VGPRs)
typedef __attribute__((ext_vector_type(4))) float f32x4;    // MFMA accumulator

__device__ __forceinline__ short f2bf(float f) {
    // round-to-nearest-even bf16 (values are finite & positive here)
    unsigned u = __float_as_uint(f);
    u += 0x7fffu + ((u >> 16) & 1u);
    return (short)(u >> 16);
}

__global__ __launch_bounds__(256) void rhyme_dp_kernel(
    const float* __restrict__ logits,   // [B,16,256]
    const int*   __restrict__ tidx,     // [B,16]
    const float* __restrict__ phon,     // [256,256], symmetric
    float*       __restrict__ out,      // [B]
    int B)
{
    __shared__ float sub_lds[4][16][17];   // per-wave 16x16 sub, +1 pad

    const int lane = threadIdx.x & 63;
    const int wv   = threadIdx.x >> 6;
    int b = blockIdx.x * 4 + wv;
    const bool valid = (b < B);
    if (!valid) b = 0;                      // clamp, compute garbage, skip store

    const int t = lane & 15;
    const int q = lane >> 4;

    // target indices: lane n (=t) owns column n of sub; phon row idxn (symmetry)
    const int idxn = tidx[b * 16 + t];
    const int idx0 = __shfl(idxn, 0);       // uniform across wave
    const int c0 = idx0 >> 5;               // which K-chunk holds v=idx0
    const int q0 = (idx0 >> 3) & 3;         // which quad
    const int j0 = idx0 & 7;                // which element in the 8-vector

    const float* lp = logits + (size_t)b * 4096 + t * 256 + q * 8;
    const float* bp = phon   + (size_t)idxn * 256 + q * 8;

    f32x4 acc = {0.f, 0.f, 0.f, 0.f};
    float zsum = 0.f;
    float e0cap = 0.f;                      // exp(logit[0][idx0]) in fp32

    #pragma unroll
    for (int c = 0; c < 8; ++c) {
        const float4 x0 = *(const float4*)(lp + c * 32);
        const float4 x1 = *(const float4*)(lp + c * 32 + 4);
        const float4 y0 = *(const float4*)(bp + c * 32);
        const float4 y1 = *(const float4*)(bp + c * 32 + 4);

        const float e0_ = __expf(x0.x), e1_ = __expf(x0.y);
        const float e2_ = __expf(x0.z), e3_ = __expf(x0.w);
        const float e4_ = __expf(x1.x), e5_ = __expf(x1.y);
        const float e6_ = __expf(x1.z), e7_ = __expf(x1.w);
        zsum += ((e0_ + e1_) + (e2_ + e3_)) + ((e4_ + e5_) + (e6_ + e7_));

        if (c == c0) {                      // wave-uniform branch
            const float a01 = (j0 & 1) ? e1_ : e0_;
            const float a23 = (j0 & 1) ? e3_ : e2_;
            const float a45 = (j0 & 1) ? e5_ : e4_;
            const float a67 = (j0 & 1) ? e7_ : e6_;
            const float b03 = (j0 & 2) ? a23 : a01;
            const float b47 = (j0 & 2) ? a67 : a45;
            const float sel = (j0 & 4) ? b47 : b03;
            if ((t == 0) && (q == q0)) e0cap = sel;
        }

        short8 af, bf;
        af[0] = f2bf(e0_); af[1] = f2bf(e1_); af[2] = f2bf(e2_); af[3] = f2bf(e3_);
        af[4] = f2bf(e4_); af[5] = f2bf(e5_); af[6] = f2bf(e6_); af[7] = f2bf(e7_);
        bf[0] = f2bf(y0.x); bf[1] = f2bf(y0.y); bf[2] = f2bf(y0.z); bf[3] = f2bf(y0.w);
        bf[4] = f2bf(y1.x); bf[5] = f2bf(y1.y); bf[6] = f2bf(y1.z); bf[7] = f2bf(y1.w);

        // D[row=q*4+r][col=t] += A[t][k] * B[k][col], k = c*32 + q*8 + j
        acc = __builtin_amdgcn_mfma_f32_16x16x32_bf16(af, bf, acc, 0, 0, 0);
    }

    // Z_t: reduce across the 4 quads holding row t (lanes t, t+16, t+32, t+48)
    zsum += __shfl_xor(zsum, 16);
    zsum += __shfl_xor(zsum, 32);
    const float rz = 1.0f / zsum;           // lane has 1/Z for its own t

    // first-char probability, all in fp32
    const float e0b = __shfl(e0cap, q0 * 16);   // lane (t=0, q=q0)
    const float rz0 = __shfl(rz, 0);            // lane 0 holds 1/Z_0
    const float p0  = e0b * rz0;

    // normalize accumulator rows by 1/Z_row and stash sub in LDS
    #pragma unroll
    for (int r = 0; r < 4; ++r) {
        const float rzr = __shfl(rz, q * 4 + r);    // lane (q*4+r) holds 1/Z_{q*4+r}
        sub_lds[wv][q * 4 + r][t] = acc[r] * rzr;
    }
    __syncthreads();   // ordering for intra-wave LDS write->read (cheap, uniform)

    // Anti-diagonal DP: lane = j-1 owns column j (j=1..16); lanes>=16 compute junk.
    // cell(i,j) = softmin3(cell(i-1,j)+10, cell(i,j-1)+10, cell(i-1,j-1)+sub[i-1][j-1])
    const int j = lane + 1;
    float P1 = 0.f, P2 = 0.f;   // own values at steps d-1, d-2
    for (int d = 2; d <= 32; ++d) {
        const int i = d - j;
        const float lnv = __shfl_up(P1, 1);     // left  = cell(i, j-1)
        const float dgv = __shfl_up(P2, 1);     // diag  = cell(i-1, j-1)
        const float up   = (i == 1) ? 10.0f * (float)j : P1;
        const float left = (j == 1) ? 10.0f * (float)i : lnv;
        const float diag = (i == 1) ? 10.0f * (float)(j - 1)
                         : ((j == 1) ? 10.0f * (float)(i - 1) : dgv);
        int row = i - 1; row = row < 0 ? 0 : (row > 15 ? 15 : row);
        const float s  = sub_lds[wv][row][t];   // col j-1 == t for lanes 0..15
        const float a  = up   + 10.0f;
        const float bb = left + 10.0f;
        const float cc = diag + s;
        const float mn = fminf(a, fminf(bb, cc));
        const float sm = __expf(mn - a) + __expf(mn - bb) + __expf(mn - cc);
        const float val = mn - __logf(sm);
        const bool act = (i >= 1) && (i <= 16);
        P2 = act ? P1 : P2;
        P1 = act ? val : P1;
    }

    if (valid && lane == 15) {
        out[b] = P1 + 10.0f * (1.0f - p0);   // dp(16,16) + FIRST_CHAR_COST*(1-p0)
    }
}

extern "C" void kernel_launch(void* const* d_in, const int* in_sizes, int n_in,
                              void* d_out, int out_size, void* d_ws, size_t ws_size,
                              hipStream_t stream) {
    const float* logits = (const float*)d_in[0];
    const int*   tidx   = (const int*)d_in[1];
    const float* phon   = (const float*)d_in[2];
    float* out = (float*)d_out;

    const int B = in_sizes[0] / (16 * 256);
    const int blocks = (B + 3) / 4;          // 4 waves (=4 batch elems) per block
    hipLaunchKernelGGL(rhyme_dp_kernel, dim3(blocks), dim3(256), 0, stream,
                       logits, tidx, phon, out, B);
}

// Round 2
// 195.746 us; speedup vs baseline: 1.0393x; 1.0393x over previous
//
#include <hip/hip_runtime.h>

// One wave = one batch element for softmax+MFMA (phase 1).
// Wave 0 of each block then runs the 4 batch elements' DPs merged (phase 2):
// lane = g*16 + (j-1), g = which batch of the block, j = DP column.
typedef __attribute__((ext_vector_type(8))) short short8;   // 8 bf16 (4 VGPRs)
typedef __attribute__((ext_vector_type(4))) float f32x4;    // MFMA accumulator
typedef __attribute__((ext_vector_type(4))) float vf4;      // vector float4

// pack two positive floats to bf16x2 with round-half-up: +0x8000 then take hi16
__device__ __forceinline__ unsigned pk_bf16(float lo, float hi) {
    const unsigned ul = __float_as_uint(lo) + 0x8000u;
    const unsigned uh = __float_as_uint(hi) + 0x8000u;
    // v_perm_b32: pool = {S0=uh bytes 7:4, S1=ul bytes 3:0};
    // result bytes = {uh.b3, uh.b2, ul.b3, ul.b2}
    return __builtin_amdgcn_perm(uh, ul, 0x07060302u);
}

__global__ __launch_bounds__(256) void rhyme_dp_kernel(
    const float* __restrict__ logits,   // [B,16,256]
    const int*   __restrict__ tidx,     // [B,16]
    const float* __restrict__ phon,     // [256,256], symmetric
    float*       __restrict__ out,      // [B]
    int B)
{
    __shared__ float sub_lds[4][16][17];   // per-wave 16x16 sub, +1 pad
    __shared__ float p0s[4];               // per-wave first-char prob

    const int lane = threadIdx.x & 63;
    const int wv   = threadIdx.x >> 6;
    int b = blockIdx.x * 4 + wv;
    if (b >= B) b = B - 1;                  // clamp; store is gated later

    const int t = lane & 15;
    const int q = lane >> 4;

    // target indices: lane n (=t) owns column n of sub; phon row idxn (symmetry)
    const int idxn = tidx[b * 16 + t];
    const int idx0 = __shfl(idxn, 0);       // uniform across wave
    const int c0 = idx0 >> 5;               // which K-chunk holds v=idx0
    const int q0 = (idx0 >> 3) & 3;         // which quad
    const int j0 = idx0 & 7;                // which element in the 8-vector

    const float* lp = logits + (size_t)b * 4096 + t * 256 + q * 8;
    const float* bp = phon   + (size_t)idxn * 256 + q * 8;

    // hoist all logits loads: 16 x dwordx4 in flight per wave
    vf4 xv[16];
    #pragma unroll
    for (int c = 0; c < 8; ++c) {
        xv[2 * c]     = *(const vf4*)(lp + c * 32);
        xv[2 * c + 1] = *(const vf4*)(lp + c * 32 + 4);
    }

    f32x4 acc = {0.f, 0.f, 0.f, 0.f};
    float zsum = 0.f;
    float e0cap = 0.f;                      // exp(logit[0][idx0]) in fp32

    #pragma unroll
    for (int c = 0; c < 8; ++c) {
        const vf4 x0 = xv[2 * c];
        const vf4 x1 = xv[2 * c + 1];
        const vf4 y0 = *(const vf4*)(bp + c * 32);
        const vf4 y1 = *(const vf4*)(bp + c * 32 + 4);

        const float e0_ = __expf(x0[0]), e1_ = __expf(x0[1]);
        const float e2_ = __expf(x0[2]), e3_ = __expf(x0[3]);
        const float e4_ = __expf(x1[0]), e5_ = __expf(x1[1]);
        const float e6_ = __expf(x1[2]), e7_ = __expf(x1[3]);
        zsum += ((e0_ + e1_) + (e2_ + e3_)) + ((e4_ + e5_) + (e6_ + e7_));

        if (c == c0) {                      // wave-uniform branch
            const float a01 = (j0 & 1) ? e1_ : e0_;
            const float a23 = (j0 & 1) ? e3_ : e2_;
            const float a45 = (j0 & 1) ? e5_ : e4_;
            const float a67 = (j0 & 1) ? e7_ : e6_;
            const float b03 = (j0 & 2) ? a23 : a01;
            const float b47 = (j0 & 2) ? a67 : a45;
            const float sel = (j0 & 4) ? b47 : b03;
            if ((t == 0) && (q == q0)) e0cap = sel;
        }

        union { short8 s; unsigned u[4]; } A, Bb;
        A.u[0] = pk_bf16(e0_, e1_); A.u[1] = pk_bf16(e2_, e3_);
        A.u[2] = pk_bf16(e4_, e5_); A.u[3] = pk_bf16(e6_, e7_);
        Bb.u[0] = pk_bf16(y0[0], y0[1]); Bb.u[1] = pk_bf16(y0[2], y0[3]);
        Bb.u[2] = pk_bf16(y1[0], y1[1]); Bb.u[3] = pk_bf16(y1[2], y1[3]);

        // D[row=q*4+r][col=t] += A[t][k] * B[k][col], k = c*32 + q*8 + j
        acc = __builtin_amdgcn_mfma_f32_16x16x32_bf16(A.s, Bb.s, acc, 0, 0, 0);
    }

    // Z_t: reduce across the 4 quads holding row t (lanes t, t+16, t+32, t+48)
    zsum += __shfl_xor(zsum, 16);
    zsum += __shfl_xor(zsum, 32);
    const float rz = 1.0f / zsum;           // lane has 1/Z for its own t

    // first-char probability, all in fp32
    const float e0b = __shfl(e0cap, q0 * 16);   // lane (t=0, q=q0)
    const float rz0 = __shfl(rz, 0);            // lane 0 holds 1/Z_0
    const float p0  = e0b * rz0;
    if (lane == 0) p0s[wv] = p0;

    // normalize accumulator rows by 1/Z_row and stash sub in LDS
    #pragma unroll
    for (int r = 0; r < 4; ++r) {
        const float rzr = __shfl(rz, q * 4 + r);    // lane (q*4+r) holds 1/Z_{q*4+r}
        sub_lds[wv][q * 4 + r][t] = acc[r] * rzr;
    }
    __syncthreads();
    if (wv != 0) return;                    // waves 1-3 done; wave 0 runs 4 DPs

    // Anti-diagonal DP, 4 problems packed: group g = lane>>4, column j = (lane&15)+1.
    // cell(i,j) = softmin3(cell(i-1,j)+10, cell(i,j-1)+10, cell(i-1,j-1)+sub[i-1][j-1])
    // shfl_up crossing a group boundary only feeds lanes with j==1, which override.
    const int g  = lane >> 4;
    const int tl = lane & 15;
    const int j  = tl + 1;
    float P1 = 0.f, P2 = 0.f;   // own values at steps d-1, d-2
    #pragma unroll
    for (int d = 2; d <= 32; ++d) {
        const float lnv = __shfl_up(P1, 1);     // left  = cell(i, j-1)
        const float dgv = __shfl_up(P2, 1);     // diag  = cell(i-1, j-1)
        const int i = d - j;
        const float up   = (i == 1) ? 10.0f * (float)j : P1;
        const float left = (j == 1) ? 10.0f * (float)i : lnv;
        const float diag = (i == 1) ? 10.0f * (float)(j - 1)
                         : ((j == 1) ? 10.0f * (float)(i - 1) : dgv);
        int row = i - 1; row = row < 0 ? 0 : (row > 15 ? 15 : row);
        const float s  = sub_lds[g][row][tl];
        const float a  = up   + 10.0f;
        const float bb = left + 10.0f;
        const float cc = diag + s;
        const float mn = fminf(a, fminf(bb, cc));
        const float sm = __expf(mn - a) + __expf(mn - bb) + __expf(mn - cc);
        const float val = mn - __logf(sm);
        const bool act = (i >= 1) && (i <= 16);
        P2 = act ? P1 : P2;
        P1 = act ? val : P1;
    }

    const int gb = blockIdx.x * 4 + g;
    if (tl == 15 && gb < B) {
        out[gb] = P1 + 10.0f * (1.0f - p0s[g]);   // dp(16,16) + 10*(1-p0)
    }
}

extern "C" void kernel_launch(void* const* d_in, const int* in_sizes, int n_in,
                              void* d_out, int out_size, void* d_ws, size_t ws_size,
                              hipStream_t stream) {
    const float* logits = (const float*)d_in[0];
    const int*   tidx   = (const int*)d_in[1];
    const float* phon   = (const float*)d_in[2];
    float* out = (float*)d_out;

    const int B = in_sizes[0] / (16 * 256);
    const int blocks = (B + 3) / 4;          // 4 waves (=4 batch elems) per block
    hipLaunchKernelGGL(rhyme_dp_kernel, dim3(blocks), dim3(256), 0, stream,
                       logits, tidx, phon, out, B);
}